// Round 5
// baseline (156.624 us; speedup 1.0000x reference)
//
#include <hip/hip_runtime.h>
#include <hip/hip_bf16.h>

// Fused op: out = cos(x @ W_in^T + theta) @ W_out^T
// x: [262144, 64] f32, W_in: [64,64] f32, theta: [64] f32, W_out: [64,64] f32
// out: [262144, 64] f32
//
// Split into two phase-homogeneous streaming kernels, bouncing q (bf16,
// 33.5 MB) through d_ws, which stays in the 256 MB Infinity Cache:
//   K1: q = cos(x @ W_in^T + theta)   -- read-dominant (x from HBM)
//   K2: out = q @ W_out^T             -- write-dominant (out to HBM)
// K1 stores q DIRECTLY from the MFMA D-layout (4 consecutive w per lane ->
// 8B stores forming full 32B sectors); K2 loads those bytes back as ready
// B-fragments. No LDS anywhere, short per-wave chains, 32 blocks/CU queued.

typedef __attribute__((ext_vector_type(8))) short bf16x8;   // 8 bf16 in 4 VGPRs
typedef __attribute__((ext_vector_type(4))) float f32x4;

#define INV2PI 0.15915493667125702f

static __device__ __forceinline__ unsigned int pk2(float a, float b) {
  // 2 x f32 -> packed bf16x2 via HW v_cvt_pk_bf16_f32 (RNE)
  __hip_bfloat162 h = __float22bfloat162_rn(make_float2(a, b));
  union { __hip_bfloat162 h; unsigned int u; } u;
  u.h = h;
  return u.u;
}

static __device__ __forceinline__ bf16x8 cvt8(f32x4 a, f32x4 b) {
  union { bf16x8 v; __hip_bfloat162 h[4]; } u;
  u.h[0] = __float22bfloat162_rn(make_float2(a[0], a[1]));
  u.h[1] = __float22bfloat162_rn(make_float2(a[2], a[3]));
  u.h[2] = __float22bfloat162_rn(make_float2(b[0], b[1]));
  u.h[3] = __float22bfloat162_rn(make_float2(b[2], b[3]));
  return u.v;
}

// ---------------- K1: q = cos(x @ W_in^T + theta), 32 rows/wave ----------------
__global__ __launch_bounds__(64, 4) void mhaq_k1(
    const float* __restrict__ x, const float* __restrict__ Win,
    const float* __restrict__ theta, unsigned short* __restrict__ q)
{
  const int lane = threadIdx.x & 63;
  const int g    = lane >> 4;            // 0..3
  const int c    = lane & 15;            // 0..15
  const long rowb = (long)blockIdx.x * 32;

  // all 8 raw x dwordx4 loads in flight first (B-frags: m=c+16mt, k=32ks+8g+j)
  f32x4 raw[8];
  #pragma unroll
  for (int mt = 0; mt < 2; ++mt) {
    #pragma unroll
    for (int ks = 0; ks < 2; ++ks) {
      const float* p = x + (rowb + c + 16*mt) * 64 + 32*ks + 8*g;
      raw[(mt*2 + ks)*2 + 0] = *(const f32x4*)p;
      raw[(mt*2 + ks)*2 + 1] = *(const f32x4*)(p + 4);
    }
  }

  // W_in as A-fragments: rows w = c + 16*wt, k = e = 32*ks + 8*g + j (L2-hot)
  bf16x8 aWin[4][2];
  #pragma unroll
  for (int wt = 0; wt < 4; ++wt) {
    #pragma unroll
    for (int ks = 0; ks < 2; ++ks) {
      const float* p = Win + (c + 16*wt) * 64 + 32*ks + 8*g;
      aWin[wt][ks] = cvt8(*(const f32x4*)p, *(const f32x4*)(p + 4));
    }
  }
  // theta * 1/(2pi); element r maps to w = 16*wt + 4*g + r
  f32x4 th[4];
  #pragma unroll
  for (int wt = 0; wt < 4; ++wt) {
    f32x4 t = *(const f32x4*)(theta + 16*wt + 4*g);
    th[wt] = t * INV2PI;
  }

  // cvt raw -> B-fragments (waits on x loads here)
  bf16x8 bx[2][2];
  #pragma unroll
  for (int mt = 0; mt < 2; ++mt) {
    #pragma unroll
    for (int ks = 0; ks < 2; ++ks) {
      bx[mt][ks] = cvt8(raw[(mt*2 + ks)*2], raw[(mt*2 + ks)*2 + 1]);
    }
  }

  // matmul1 + cos + direct q store (D layout: col m=c+16mt, row w=4g+r+16wt)
  #pragma unroll
  for (int wt = 0; wt < 4; ++wt) {
    f32x4 acc[2];
    #pragma unroll
    for (int mt = 0; mt < 2; ++mt) {
      f32x4 a = {0.f, 0.f, 0.f, 0.f};
      a = __builtin_amdgcn_mfma_f32_16x16x32_bf16(aWin[wt][0], bx[mt][0], a, 0, 0, 0);
      a = __builtin_amdgcn_mfma_f32_16x16x32_bf16(aWin[wt][1], bx[mt][1], a, 0, 0, 0);
      acc[mt] = a;
    }
    #pragma unroll
    for (int mt = 0; mt < 2; ++mt) {
      float qv[4];
      #pragma unroll
      for (int r = 0; r < 4; ++r) {
        float rev = acc[mt][r] * INV2PI + th[wt][r];
        rev -= floorf(rev);                      // range-reduce to [0,1)
        qv[r] = __builtin_amdgcn_cosf(rev);      // v_cos_f32: cos(2*pi*rev)
      }
      // q[m][w..w+3] bf16: 8B store, 4 g-lanes form a full 32B sector
      *(uint2*)(q + (rowb + c + 16*mt) * 64 + 16*wt + 4*g) =
          make_uint2(pk2(qv[0], qv[1]), pk2(qv[2], qv[3]));
    }
  }
}

// ---------------- K2: out = q @ W_out^T, 32 rows/wave ----------------
__global__ __launch_bounds__(64, 4) void mhaq_k2(
    const unsigned short* __restrict__ q, const float* __restrict__ Wout,
    float* __restrict__ out)
{
  const int lane = threadIdx.x & 63;
  const int g    = lane >> 4;
  const int c    = lane & 15;
  const long rowb = (long)blockIdx.x * 32;

  // q rows are already bf16 in B-fragment order: col m=c+16mt, k=w=32ks+8g+j
  bf16x8 qf[2][2];
  #pragma unroll
  for (int mt = 0; mt < 2; ++mt) {
    #pragma unroll
    for (int ks = 0; ks < 2; ++ks) {
      qf[mt][ks] = *(const bf16x8*)(q + (rowb + c + 16*mt) * 64 + 32*ks + 8*g);
    }
  }

  // W_out as A-fragments: rows o = c + 16*ot, k = w = 32*ks + 8*g + j (L2-hot)
  bf16x8 aWout[4][2];
  #pragma unroll
  for (int ot = 0; ot < 4; ++ot) {
    #pragma unroll
    for (int ks = 0; ks < 2; ++ks) {
      const float* p = Wout + (c + 16*ot) * 64 + 32*ks + 8*g;
      aWout[ot][ks] = cvt8(*(const f32x4*)p, *(const f32x4*)(p + 4));
    }
  }

  // matmul2 + cached coalesced f32x4 stores (D2[o][m] = out[m][o])
  #pragma unroll
  for (int ot = 0; ot < 4; ++ot) {
    f32x4 acc[2];
    #pragma unroll
    for (int mt = 0; mt < 2; ++mt) {
      f32x4 a = {0.f, 0.f, 0.f, 0.f};
      a = __builtin_amdgcn_mfma_f32_16x16x32_bf16(aWout[ot][0], qf[mt][0], a, 0, 0, 0);
      a = __builtin_amdgcn_mfma_f32_16x16x32_bf16(aWout[ot][1], qf[mt][1], a, 0, 0, 0);
      acc[mt] = a;
    }
    #pragma unroll
    for (int mt = 0; mt < 2; ++mt) {
      *(f32x4*)(out + (rowb + c + 16*mt) * 64 + 16*ot + 4*g) = acc[mt];
    }
  }
}

// ---------------- fallback: round-4 fused kernel (if ws too small) ----------------
__global__ __launch_bounds__(64, 4) void mhaq_fused(
    const float* __restrict__ x, const float* __restrict__ Win,
    const float* __restrict__ theta, const float* __restrict__ Wout,
    float* __restrict__ out)
{
  const int lane = threadIdx.x & 63;
  const int g    = lane >> 4;
  const int c    = lane & 15;
  const long rowb = (long)blockIdx.x * 64;

  __shared__ char lds[64 * 128];

  f32x4 raw[16];
  #pragma unroll
  for (int mt = 0; mt < 4; ++mt)
    #pragma unroll
    for (int ks = 0; ks < 2; ++ks) {
      const float* p = x + (rowb + c + 16*mt) * 64 + 32*ks + 8*g;
      raw[(mt*2 + ks)*2 + 0] = *(const f32x4*)p;
      raw[(mt*2 + ks)*2 + 1] = *(const f32x4*)(p + 4);
    }

  bf16x8 aWin[4][2];
  #pragma unroll
  for (int wt = 0; wt < 4; ++wt)
    #pragma unroll
    for (int ks = 0; ks < 2; ++ks) {
      const float* p = Win + (c + 16*wt) * 64 + 32*ks + 8*g;
      aWin[wt][ks] = cvt8(*(const f32x4*)p, *(const f32x4*)(p + 4));
    }
  bf16x8 aWout[4][2];
  #pragma unroll
  for (int ot = 0; ot < 4; ++ot)
    #pragma unroll
    for (int ks = 0; ks < 2; ++ks) {
      const float* p = Wout + (c + 16*ot) * 64 + 32*ks + 8*g;
      aWout[ot][ks] = cvt8(*(const f32x4*)p, *(const f32x4*)(p + 4));
    }
  f32x4 th[4];
  #pragma unroll
  for (int wt = 0; wt < 4; ++wt) {
    f32x4 t = *(const f32x4*)(theta + 16*wt + 4*g);
    th[wt] = t * INV2PI;
  }

  bf16x8 bx[4][2];
  #pragma unroll
  for (int mt = 0; mt < 4; ++mt)
    #pragma unroll
    for (int ks = 0; ks < 2; ++ks)
      bx[mt][ks] = cvt8(raw[(mt*2 + ks)*2], raw[(mt*2 + ks)*2 + 1]);

  #pragma unroll
  for (int wt = 0; wt < 4; ++wt) {
    f32x4 acc[4];
    #pragma unroll
    for (int mt = 0; mt < 4; ++mt) {
      f32x4 a = {0.f, 0.f, 0.f, 0.f};
      a = __builtin_amdgcn_mfma_f32_16x16x32_bf16(aWin[wt][0], bx[mt][0], a, 0, 0, 0);
      a = __builtin_amdgcn_mfma_f32_16x16x32_bf16(aWin[wt][1], bx[mt][1], a, 0, 0, 0);
      acc[mt] = a;
    }
    #pragma unroll
    for (int mt = 0; mt < 4; ++mt) {
      float qv[4];
      #pragma unroll
      for (int r = 0; r < 4; ++r) {
        float rev = acc[mt][r] * INV2PI + th[wt][r];
        rev -= floorf(rev);
        qv[r] = __builtin_amdgcn_cosf(rev);
      }
      const int m = c + 16*mt;
      int off = m * 128 + (16*wt + 4*g) * 2;
      off ^= (m & 7) << 4;
      *(uint2*)(lds + off) = make_uint2(pk2(qv[0], qv[1]), pk2(qv[2], qv[3]));
    }
  }

  asm volatile("s_waitcnt lgkmcnt(0)" ::: "memory");

  bf16x8 qf[4][2];
  #pragma unroll
  for (int mt = 0; mt < 4; ++mt)
    #pragma unroll
    for (int ks = 0; ks < 2; ++ks) {
      const int m = c + 16*mt;
      int off = m * 128 + (32*ks + 8*g) * 2;
      off ^= (m & 7) << 4;
      qf[mt][ks] = *(const bf16x8*)(lds + off);
    }

  #pragma unroll
  for (int ot = 0; ot < 4; ++ot) {
    f32x4 acc[4];
    #pragma unroll
    for (int mt = 0; mt < 4; ++mt) {
      f32x4 a = {0.f, 0.f, 0.f, 0.f};
      a = __builtin_amdgcn_mfma_f32_16x16x32_bf16(aWout[ot][0], qf[mt][0], a, 0, 0, 0);
      a = __builtin_amdgcn_mfma_f32_16x16x32_bf16(aWout[ot][1], qf[mt][1], a, 0, 0, 0);
      acc[mt] = a;
    }
    #pragma unroll
    for (int mt = 0; mt < 4; ++mt)
      *(f32x4*)(out + (rowb + c + 16*mt) * 64 + 16*ot + 4*g) = acc[mt];
  }
}

extern "C" void kernel_launch(void* const* d_in, const int* in_sizes, int n_in,
                              void* d_out, int out_size, void* d_ws, size_t ws_size,
                              hipStream_t stream) {
  const float* x     = (const float*)d_in[0];
  const float* Win   = (const float*)d_in[1];
  const float* theta = (const float*)d_in[2];
  const float* Wout  = (const float*)d_in[3];
  float* out = (float*)d_out;

  const long rows    = (long)in_sizes[0] / 64;       // 262144
  const size_t q_bytes = (size_t)rows * 64 * 2;      // 33.5 MB bf16

  if (ws_size >= q_bytes) {
    unsigned short* q = (unsigned short*)d_ws;
    dim3 block(64);
    dim3 grid1((unsigned)(rows / 32));               // 8192
    hipLaunchKernelGGL(mhaq_k1, grid1, block, 0, stream, x, Win, theta, q);
    hipLaunchKernelGGL(mhaq_k2, grid1, block, 0, stream, q, Wout, out);
  } else {
    dim3 grid((unsigned)(rows / 64)), block(64);     // 4096
    hipLaunchKernelGGL(mhaq_fused, grid, block, 0, stream, x, Win, theta, Wout, out);
  }
}

// Round 6
// 127.134 us; speedup vs baseline: 1.2320x; 1.2320x over previous
//
#include <hip/hip_runtime.h>
#include <hip/hip_bf16.h>

// Fused: out = cos(x @ W_in^T + theta) @ W_out^T
// x: [262144, 64] f32, W_in: [64,64] f32, theta: [64] f32, W_out: [64,64] f32
// out: [262144, 64] f32
//
// 4096 blocks x 64 threads (1 wave each, ~16 waves/CU). KEY FIX vs all prior
// rounds: a sched_barrier(0) after the 16 x dwordx4 loads forbids the
// scheduler from sinking conversions between them — all 16 loads are in
// flight per wave (prior rounds compiled to VGPR=36..64, i.e. serialized
// loads, 4-8x exposed HBM latency). W_out fragments are loaded AFTER
// matmul1 so the grouped-load peak (~124 VGPR) fits the 128/4-wave cap.

typedef __attribute__((ext_vector_type(8))) short bf16x8;   // 8 bf16 in 4 VGPRs
typedef __attribute__((ext_vector_type(4))) float f32x4;

#define INV2PI 0.15915493667125702f

static __device__ __forceinline__ unsigned int pk2(float a, float b) {
  // 2 x f32 -> packed bf16x2 via HW v_cvt_pk_bf16_f32 (RNE)
  __hip_bfloat162 h = __float22bfloat162_rn(make_float2(a, b));
  union { __hip_bfloat162 h; unsigned int u; } u;
  u.h = h;
  return u.u;
}

static __device__ __forceinline__ bf16x8 cvt8(f32x4 a, f32x4 b) {
  union { bf16x8 v; __hip_bfloat162 h[4]; } u;
  u.h[0] = __float22bfloat162_rn(make_float2(a[0], a[1]));
  u.h[1] = __float22bfloat162_rn(make_float2(a[2], a[3]));
  u.h[2] = __float22bfloat162_rn(make_float2(b[0], b[1]));
  u.h[3] = __float22bfloat162_rn(make_float2(b[2], b[3]));
  return u.v;
}

__global__ __launch_bounds__(64, 4) void mhaq_fused(
    const float* __restrict__ x, const float* __restrict__ Win,
    const float* __restrict__ theta, const float* __restrict__ Wout,
    float* __restrict__ out)
{
  const int lane = threadIdx.x & 63;
  const int g    = lane >> 4;            // lane group 0..3
  const int c    = lane & 15;            // 0..15
  const long rowb = (long)blockIdx.x * 64;

  // wave-private 64x64 bf16 q tile (8 KB), XOR-swizzled rows
  __shared__ char lds[64 * 128];

  // ---- issue ALL 16 raw x dwordx4 loads back-to-back ----
  // fragment (mt,ks): cols m = c + 16*mt, k = e = 32*ks + 8*g + j
  f32x4 raw[16];
  #pragma unroll
  for (int mt = 0; mt < 4; ++mt) {
    #pragma unroll
    for (int ks = 0; ks < 2; ++ks) {
      const float* p = x + (rowb + c + 16*mt) * 64 + 32*ks + 8*g;
      raw[(mt*2 + ks)*2 + 0] = *(const f32x4*)p;
      raw[(mt*2 + ks)*2 + 1] = *(const f32x4*)(p + 4);
    }
  }
  // HARD FENCE: nothing (esp. the cvts below) may be scheduled above this,
  // so all 16 loads issue as one burst and fly concurrently.
  __builtin_amdgcn_sched_barrier(0);

  // ---- W_in as A-fragments (L1/L2-hot broadcast): rows w=c+16wt, k=32ks+8g+j ----
  bf16x8 aWin[4][2];
  #pragma unroll
  for (int wt = 0; wt < 4; ++wt) {
    #pragma unroll
    for (int ks = 0; ks < 2; ++ks) {
      const float* p = Win + (c + 16*wt) * 64 + 32*ks + 8*g;
      aWin[wt][ks] = cvt8(*(const f32x4*)p, *(const f32x4*)(p + 4));
    }
  }
  // theta * 1/(2pi); element r maps to w = 16*wt + 4*g + r
  f32x4 th[4];
  #pragma unroll
  for (int wt = 0; wt < 4; ++wt) {
    f32x4 t = *(const f32x4*)(theta + 16*wt + 4*g);
    th[wt] = t * INV2PI;
  }

  // ---- cvt raw -> B-fragments (progressive vmcnt waits) ----
  bf16x8 bx[4][2];
  #pragma unroll
  for (int mt = 0; mt < 4; ++mt) {
    #pragma unroll
    for (int ks = 0; ks < 2; ++ks) {
      bx[mt][ks] = cvt8(raw[(mt*2 + ks)*2], raw[(mt*2 + ks)*2 + 1]);
    }
  }

  // ---- matmul1 (wt at a time) + cos + pack -> LDS ----
  // D layout: col m = c (+16*mt tile), row w = 4*g + r (+16*wt tile)
  #pragma unroll
  for (int wt = 0; wt < 4; ++wt) {
    f32x4 acc[4];
    #pragma unroll
    for (int mt = 0; mt < 4; ++mt) {
      f32x4 a = {0.f, 0.f, 0.f, 0.f};
      a = __builtin_amdgcn_mfma_f32_16x16x32_bf16(aWin[wt][0], bx[mt][0], a, 0, 0, 0);
      a = __builtin_amdgcn_mfma_f32_16x16x32_bf16(aWin[wt][1], bx[mt][1], a, 0, 0, 0);
      acc[mt] = a;
    }
    #pragma unroll
    for (int mt = 0; mt < 4; ++mt) {
      float qv[4];
      #pragma unroll
      for (int r = 0; r < 4; ++r) {
        float rev = acc[mt][r] * INV2PI + th[wt][r];
        rev -= floorf(rev);                      // range-reduce to [0,1)
        qv[r] = __builtin_amdgcn_cosf(rev);      // v_cos_f32: cos(2*pi*rev)
      }
      const int m = c + 16*mt;
      int off = m * 128 + (16*wt + 4*g) * 2;     // q[m][w] row-major, bf16
      off ^= (m & 7) << 4;                       // bank-conflict swizzle
      *(uint2*)(lds + off) = make_uint2(pk2(qv[0], qv[1]), pk2(qv[2], qv[3]));
    }
  }

  // wave-local LDS write->read ordering (tile is private to this wave)
  asm volatile("s_waitcnt lgkmcnt(0)" ::: "memory");
  __builtin_amdgcn_sched_barrier(0);

  // ---- W_out as A-fragments (loaded AFTER matmul1: raw[] regs are dead) ----
  bf16x8 aWout[4][2];
  #pragma unroll
  for (int ot = 0; ot < 4; ++ot) {
    #pragma unroll
    for (int ks = 0; ks < 2; ++ks) {
      const float* p = Wout + (c + 16*ot) * 64 + 32*ks + 8*g;
      aWout[ot][ks] = cvt8(*(const f32x4*)p, *(const f32x4*)(p + 4));
    }
  }

  // ---- q back as B-fragments: col m = c + 16*mt, k = w = 32*ks + 8*g + j ----
  bf16x8 qf[4][2];
  #pragma unroll
  for (int mt = 0; mt < 4; ++mt) {
    #pragma unroll
    for (int ks = 0; ks < 2; ++ks) {
      const int m = c + 16*mt;
      int off = m * 128 + (32*ks + 8*g) * 2;
      off ^= (m & 7) << 4;                       // same swizzle as write
      qf[mt][ks] = *(const bf16x8*)(lds + off);  // ds_read_b128
    }
  }

  // ---- matmul2 (ot at a time) + cached coalesced float4 stores ----
  // D2[o][m] = out[m][o]; col m = c (+16*mt), row o = 4*g + r (+16*ot)
  #pragma unroll
  for (int ot = 0; ot < 4; ++ot) {
    f32x4 acc[4];
    #pragma unroll
    for (int mt = 0; mt < 4; ++mt) {
      f32x4 a = {0.f, 0.f, 0.f, 0.f};
      a = __builtin_amdgcn_mfma_f32_16x16x32_bf16(aWout[ot][0], qf[mt][0], a, 0, 0, 0);
      a = __builtin_amdgcn_mfma_f32_16x16x32_bf16(aWout[ot][1], qf[mt][1], a, 0, 0, 0);
      acc[mt] = a;
    }
    #pragma unroll
    for (int mt = 0; mt < 4; ++mt) {
      *(f32x4*)(out + (rowb + c + 16*mt) * 64 + 16*ot + 4*g) = acc[mt];
    }
  }
}

extern "C" void kernel_launch(void* const* d_in, const int* in_sizes, int n_in,
                              void* d_out, int out_size, void* d_ws, size_t ws_size,
                              hipStream_t stream) {
  const float* x     = (const float*)d_in[0];
  const float* Win   = (const float*)d_in[1];
  const float* theta = (const float*)d_in[2];
  const float* Wout  = (const float*)d_in[3];
  float* out = (float*)d_out;

  // 262144 rows / 64 rows-per-wave = 4096 single-wave blocks
  dim3 grid(4096), block(64);
  hipLaunchKernelGGL(mhaq_fused, grid, block, 0, stream, x, Win, theta, Wout, out);
}